// Round 2
// baseline (251.802 us; speedup 1.0000x reference)
//
#include <hip/hip_runtime.h>
#include <hip/hip_bf16.h>

// GraphSAGE 2-layer forward — CSR-gather + bf16 MFMA GEMMs.
//   zl = x@W1l, zr = x@W1r     (bf16 MFMA, SPLIT packed arrays [n,64])
//   h  = sigmoid(csr_mean(zl) + zr + b1)        (h bf16 [n,64])
//   ql = h@W2l, qr = h@W2r     (split packed [n,40])
//   out = csr_mean(ql) + qr + b2                (fp32 [n,40])
//
// R2 changes vs 248µs:
//  - hist is distributed across ALL gemm-l1 blocks (384 edges each), atomics
//    issued before LDS staging so their latency hides under the GEMM. No more
//    dedicated hist blocks serialized ahead of the GEMM tiles.
//  - scan_blocks/scan_top/scan_add merged into ONE kernel (publish-then-wait
//    parallel lookback across 49 co-resident blocks).
//  - agg for F=64 uses dwordx4 gathers: 8 lanes x 16B = one row, 8 edges per
//    gather instruction; shfl_xor(8/16/32) combine; packed 16B epilogue.

#define N_FEAT 128
#define HID 64
#define NCLS 40

typedef short short8 __attribute__((ext_vector_type(8)));
typedef float floatx4 __attribute__((ext_vector_type(4)));

static __device__ __forceinline__ short f2bf(float x) {
    __hip_bfloat16 h = __float2bfloat16(x);
    return __builtin_bit_cast(short, h);
}
static __device__ __forceinline__ float bf2f(unsigned short u) {
    unsigned int v = ((unsigned int)u) << 16;
    return __builtin_bit_cast(float, v);
}

// ---------------------------------------------------------------------------
// Weight prep (transpose + cvt to bf16, concatenated [l|r]) + zero deg/flags.
// wt1[n=0..127][k=0..127], wt2[n=0..79][k=0..63]
// ---------------------------------------------------------------------------
__global__ void prep_w(const float* __restrict__ W1l, const float* __restrict__ W1r,
                       const float* __restrict__ W2l, const float* __restrict__ W2r,
                       unsigned short* __restrict__ wt1,
                       unsigned short* __restrict__ wt2,
                       int* __restrict__ deg, int* __restrict__ flags, int n) {
    int i = blockIdx.x * blockDim.x + threadIdx.x;
    if (i < 128 * 128) {
        int nn = i >> 7, k = i & 127;
        float v = (nn < 64) ? W1l[k * 64 + nn] : W1r[k * 64 + (nn - 64)];
        wt1[nn * 128 + k] = (unsigned short)f2bf(v);
    } else if (i < 128 * 128 + 80 * 64) {
        int j = i - 128 * 128;
        int nn = j >> 6, k = j & 63;
        float v = (nn < 40) ? W2l[k * 40 + nn] : W2r[k * 40 + (nn - 40)];
        wt2[nn * 64 + k] = (unsigned short)f2bf(v);
    }
    if (i < n) deg[i] = 0;
    if (i < 64) flags[i] = 0;
}

// ---------------------------------------------------------------------------
// Fused CSR-offset scan: per-block local scan + publish aggregate + parallel
// lookback (all nb<=64 blocks co-resident; publish happens BEFORE any wait,
// so no scheduling-order assumption can deadlock).
// ---------------------------------------------------------------------------
__global__ void scan_fused(const int* __restrict__ deg, int* __restrict__ off,
                           int n, int* __restrict__ bsums,
                           int* __restrict__ flags) {
    __shared__ int lds[256];
    __shared__ int look[64];
    __shared__ int sprefix;
    const int b = blockIdx.x, t = threadIdx.x;
    const int base = b * 2048 + t * 8;
    int v[8], s = 0;
#pragma unroll
    for (int i = 0; i < 8; ++i) {
        int idx = base + i;
        v[i] = (idx < n) ? deg[idx] : 0;
        s += v[i];
    }
    lds[t] = s;
    __syncthreads();
    for (int o = 1; o < 256; o <<= 1) {
        int y = (t >= o) ? lds[t - o] : 0;
        __syncthreads();
        lds[t] += y;
        __syncthreads();
    }
    // publish this block's aggregate (release: bsums visible before flag)
    if (t == 255) {
        __hip_atomic_store(&bsums[b], lds[255], __ATOMIC_RELEASE,
                           __HIP_MEMORY_SCOPE_AGENT);
        __hip_atomic_store(&flags[b], 1, __ATOMIC_RELEASE,
                           __HIP_MEMORY_SCOPE_AGENT);
    }
    if (t < 64) look[t] = 0;
    __syncthreads();
    if (t < b) {
        while (__hip_atomic_load(&flags[t], __ATOMIC_ACQUIRE,
                                 __HIP_MEMORY_SCOPE_AGENT) == 0) {}
        look[t] = __hip_atomic_load(&bsums[t], __ATOMIC_RELAXED,
                                    __HIP_MEMORY_SCOPE_AGENT);
    }
    __syncthreads();
    if (t == 0) {
        int p = 0;
        for (int i = 0; i < b; ++i) p += look[i];
        sprefix = p;
    }
    __syncthreads();
    int run = ((t == 0) ? 0 : lds[t - 1]) + sprefix;
#pragma unroll
    for (int i = 0; i < 8; ++i) {
        run += v[i];
        int idx = base + i;
        if (idx < n) off[idx + 1] = run;
    }
    if (b == 0 && t == 0) off[0] = 0;
}

// atomic-free CSR fill: slot = off[dst] + rank (rank captured during hist)
__global__ void fill_csr(const int* __restrict__ ei, const int* __restrict__ off,
                         const int* __restrict__ rank, int* __restrict__ csr,
                         int ne) {
    int e = blockIdx.x * blockDim.x + threadIdx.x;
    if (e < ne) {
        int d = ei[ne + e];
        csr[off[d] + rank[e]] = ei[e];
    }
}

// ---------------------------------------------------------------------------
// MFMA GEMM body: cols [0,MH) -> Zl packed [n,MH], cols [MH,2MH) -> Zr [n,MH].
// Block = 256 thr (4 waves), 64 rows/block; K fully staged in LDS (+8 pad).
// ---------------------------------------------------------------------------
template <int K, int MH, bool AF32>
static __device__ __forceinline__ void gemm_body(
    const void* __restrict__ Ain, const unsigned short* __restrict__ Wt,
    unsigned short* __restrict__ Zl, unsigned short* __restrict__ Zr, int n,
    int bid) {
    constexpr int M = 2 * MH;
    constexpr int LDA = K + 8;
    constexpr int MT = (M + 15) / 16;
    constexpr int KS = K / 32;
    constexpr int QROW = K / 8;
    __shared__ __align__(16) short At[64 * LDA];
    __shared__ __align__(16) short Bt[M * LDA];

    const int t = threadIdx.x;
    const int nodeBase = bid * 64;

    for (int q = t; q < 64 * QROW; q += 256) {
        int row = q / QROW;
        int k0 = (q % QROW) * 8;
        int node = nodeBase + row;
        short8 s = {0, 0, 0, 0, 0, 0, 0, 0};
        if (node < n) {
            if (AF32) {
                const float* A = (const float*)Ain + (size_t)node * K + k0;
                float4 v0 = *(const float4*)A;
                float4 v1 = *(const float4*)(A + 4);
                s[0] = f2bf(v0.x); s[1] = f2bf(v0.y);
                s[2] = f2bf(v0.z); s[3] = f2bf(v0.w);
                s[4] = f2bf(v1.x); s[5] = f2bf(v1.y);
                s[6] = f2bf(v1.z); s[7] = f2bf(v1.w);
            } else {
                s = *(const short8*)((const short*)Ain + (size_t)node * K + k0);
            }
        }
        *(short8*)&At[row * LDA + k0] = s;
    }
    for (int q = t; q < M * QROW; q += 256) {
        int row = q / QROW;
        int k0 = (q % QROW) * 8;
        *(short8*)&Bt[row * LDA + k0] =
            *(const short8*)((const short*)Wt + (size_t)row * K + k0);
    }
    __syncthreads();

    const int wave = t >> 6;
    const int lane = t & 63;
    const int m0 = wave * 16;
    const int fl = lane & 15;
    const int quad = lane >> 4;

    floatx4 acc[MT];
#pragma unroll
    for (int nt = 0; nt < MT; ++nt) acc[nt] = (floatx4){0.f, 0.f, 0.f, 0.f};

#pragma unroll
    for (int ks = 0; ks < KS; ++ks) {
        const int kb = ks * 32 + quad * 8;
        short8 a = *(const short8*)&At[(m0 + fl) * LDA + kb];
#pragma unroll
        for (int nt = 0; nt < MT; ++nt) {
            short8 b = *(const short8*)&Bt[(nt * 16 + fl) * LDA + kb];
            acc[nt] = __builtin_amdgcn_mfma_f32_16x16x32_bf16(a, b, acc[nt], 0, 0, 0);
        }
    }

    // epilogue: D[row=quad*4+r][col=nt*16+fl] -> split Zl/Zr (packed MH)
#pragma unroll
    for (int nt = 0; nt < MT; ++nt) {
        const int col = nt * 16 + fl;
#pragma unroll
        for (int r = 0; r < 4; ++r) {
            int node = nodeBase + m0 + quad * 4 + r;
            if (node < n) {
                unsigned short v = (unsigned short)f2bf(acc[nt][r]);
                if (col < MH)
                    Zl[(size_t)node * MH + col] = v;
                else
                    Zr[(size_t)node * MH + (col - MH)] = v;
            }
        }
    }
}

// Layer-1 GEMM with the degree histogram DISTRIBUTED across all tiles.
// Each block takes a ~384-edge slice; returning atomics are issued before
// LDS staging (latency hides under the staging drain + MFMA), rank stores
// happen after the epilogue.
__global__ __launch_bounds__(256) void gemm_l1_hist(
    const float* __restrict__ x, const unsigned short* __restrict__ wt1,
    unsigned short* __restrict__ zl, unsigned short* __restrict__ zr, int n,
    const int* __restrict__ ei, int* __restrict__ deg, int* __restrict__ rank,
    int ne) {
    const int t = threadIdx.x;
    const int epb = (ne + (int)gridDim.x - 1) / (int)gridDim.x;  // 384
    const int e0 = (int)blockIdx.x * epb;
    const int lim = (e0 + epb < ne) ? (e0 + epb) : ne;
    const int eA = e0 + t;
    const int eB = e0 + 256 + t;
    const bool doA = (eA < lim);
    const bool doB = (256 + t < epb) && (eB < lim);
    int rA = 0, rB = 0;
    if (doA) rA = atomicAdd(&deg[ei[ne + eA]], 1);
    if (doB) rB = atomicAdd(&deg[ei[ne + eB]], 1);

    gemm_body<N_FEAT, HID, true>(x, wt1, zl, zr, n, blockIdx.x);

    if (doA) rank[eA] = rA;
    if (doB) rank[eB] = rB;
    // safety for epb > 512 (never taken at this problem size)
    for (int e = e0 + 512 + t; e < lim; e += 256)
        rank[e] = atomicAdd(&deg[ei[ne + e]], 1);
}

template <int K, int MH, bool AF32>
__global__ __launch_bounds__(256) void gemm_mfma(
    const void* __restrict__ Ain, const unsigned short* __restrict__ Wt,
    unsigned short* __restrict__ Zl, unsigned short* __restrict__ Zr, int n) {
    gemm_body<K, MH, AF32>(Ain, Wt, Zl, Zr, n, blockIdx.x);
}

// ---------------------------------------------------------------------------
// CSR aggregate, F=64: one wave per node; 8 lanes x dwordx4 = one 128B row,
// so 8 edges are gathered per load instruction. shfl_xor(8/16/32) combine.
// ---------------------------------------------------------------------------
template <bool SIG>
__global__ void agg64_kernel(const unsigned short* __restrict__ Zl,
                             const unsigned short* __restrict__ Zr,
                             const int* __restrict__ off,
                             const int* __restrict__ csr,
                             const float* __restrict__ bias,
                             void* __restrict__ out, int n) {
    const int node = blockIdx.x * (blockDim.x >> 6) + (threadIdx.x >> 6);
    if (node >= n) return;
    const int lane = threadIdx.x & 63;
    const int start = off[node];
    const int end = off[node + 1];
    const int g = lane >> 3;   // edge slot 0..7
    const int c = lane & 7;    // 16B chunk: feats [8c, 8c+8)

    float a0 = 0.f, a1 = 0.f, a2 = 0.f, a3 = 0.f;
    float a4 = 0.f, a5 = 0.f, a6 = 0.f, a7 = 0.f;
    for (int e = start; e < end; e += 8) {
        int ee = e + g;
        int idx = csr[(ee < end) ? ee : (end - 1)];
        float w = (ee < end) ? 1.f : 0.f;
        uint4 d = *(const uint4*)(Zl + (size_t)idx * 64 + c * 8);
        a0 = fmaf(w, bf2f((unsigned short)(d.x & 0xffffu)), a0);
        a1 = fmaf(w, bf2f((unsigned short)(d.x >> 16)), a1);
        a2 = fmaf(w, bf2f((unsigned short)(d.y & 0xffffu)), a2);
        a3 = fmaf(w, bf2f((unsigned short)(d.y >> 16)), a3);
        a4 = fmaf(w, bf2f((unsigned short)(d.z & 0xffffu)), a4);
        a5 = fmaf(w, bf2f((unsigned short)(d.z >> 16)), a5);
        a6 = fmaf(w, bf2f((unsigned short)(d.w & 0xffffu)), a6);
        a7 = fmaf(w, bf2f((unsigned short)(d.w >> 16)), a7);
    }
#pragma unroll
    for (int o = 8; o < 64; o <<= 1) {
        a0 += __shfl_xor(a0, o); a1 += __shfl_xor(a1, o);
        a2 += __shfl_xor(a2, o); a3 += __shfl_xor(a3, o);
        a4 += __shfl_xor(a4, o); a5 += __shfl_xor(a5, o);
        a6 += __shfl_xor(a6, o); a7 += __shfl_xor(a7, o);
    }
    if (g == 0) {
        float inv = 1.0f / fmaxf((float)(end - start), 1.0f);
        uint4 z = *(const uint4*)(Zr + (size_t)node * 64 + c * 8);
        float4 b0 = ((const float4*)bias)[c * 2];
        float4 b1 = ((const float4*)bias)[c * 2 + 1];
        float r0 = a0 * inv + bf2f((unsigned short)(z.x & 0xffffu)) + b0.x;
        float r1 = a1 * inv + bf2f((unsigned short)(z.x >> 16)) + b0.y;
        float r2 = a2 * inv + bf2f((unsigned short)(z.y & 0xffffu)) + b0.z;
        float r3 = a3 * inv + bf2f((unsigned short)(z.y >> 16)) + b0.w;
        float r4 = a4 * inv + bf2f((unsigned short)(z.z & 0xffffu)) + b1.x;
        float r5 = a5 * inv + bf2f((unsigned short)(z.z >> 16)) + b1.y;
        float r6 = a6 * inv + bf2f((unsigned short)(z.w & 0xffffu)) + b1.z;
        float r7 = a7 * inv + bf2f((unsigned short)(z.w >> 16)) + b1.w;
        if (SIG) {
            r0 = 1.0f / (1.0f + __expf(-r0));
            r1 = 1.0f / (1.0f + __expf(-r1));
            r2 = 1.0f / (1.0f + __expf(-r2));
            r3 = 1.0f / (1.0f + __expf(-r3));
            r4 = 1.0f / (1.0f + __expf(-r4));
            r5 = 1.0f / (1.0f + __expf(-r5));
            r6 = 1.0f / (1.0f + __expf(-r6));
            r7 = 1.0f / (1.0f + __expf(-r7));
        }
        uint4 p;
        p.x = (unsigned int)(unsigned short)f2bf(r0) |
              ((unsigned int)(unsigned short)f2bf(r1) << 16);
        p.y = (unsigned int)(unsigned short)f2bf(r2) |
              ((unsigned int)(unsigned short)f2bf(r3) << 16);
        p.z = (unsigned int)(unsigned short)f2bf(r4) |
              ((unsigned int)(unsigned short)f2bf(r5) << 16);
        p.w = (unsigned int)(unsigned short)f2bf(r6) |
              ((unsigned int)(unsigned short)f2bf(r7) << 16);
        *(uint4*)((unsigned short*)out + (size_t)node * 64 + c * 8) = p;
    }
}

// ---------------------------------------------------------------------------
// CSR aggregate, F=40 (layer 2): dword gathers, 2 edges per load, fp32 out.
// ---------------------------------------------------------------------------
__global__ void agg40_kernel(const unsigned short* __restrict__ Zl,
                             const unsigned short* __restrict__ Zr,
                             const int* __restrict__ off,
                             const int* __restrict__ csr,
                             const float* __restrict__ bias,
                             float* __restrict__ out, int n) {
    constexpr int F = NCLS;
    constexpr int FD = F / 2;  // 20 dwords per row
    const int node = blockIdx.x * (blockDim.x >> 6) + (threadIdx.x >> 6);
    if (node >= n) return;
    const int lane = threadIdx.x & 63;
    const int start = off[node];
    const int end = off[node + 1];
    const int half = lane >> 5;
    const int col = lane & 31;
    float ax = 0.f, ay = 0.f;
    for (int e = start; e < end; e += 8) {
        int idx[8];
#pragma unroll
        for (int i = 0; i < 8; ++i) {
            int ee = (e + i < end) ? (e + i) : (end - 1);
            idx[i] = csr[ee];
        }
#pragma unroll
        for (int i = 0; i < 4; ++i) {
            unsigned int d = 0;
            if (col < FD)
                d = *(const unsigned int*)(Zl + (size_t)idx[2 * i + half] * F +
                                           2 * col);
            float w = (e + 2 * i + half < end) ? 1.f : 0.f;
            ax += w * bf2f((unsigned short)(d & 0xffffu));
            ay += w * bf2f((unsigned short)(d >> 16));
        }
    }
    ax += __shfl_xor(ax, 32);
    ay += __shfl_xor(ay, 32);
    if (lane < FD) {
        float inv = 1.0f / fmaxf((float)(end - start), 1.0f);
        unsigned int z =
            *(const unsigned int*)(Zr + (size_t)node * F + 2 * lane);
        float2 bb = ((const float2*)bias)[lane];
        float rx = ax * inv + bf2f((unsigned short)(z & 0xffffu)) + bb.x;
        float ry = ay * inv + bf2f((unsigned short)(z >> 16)) + bb.y;
        float2 o = {rx, ry};
        ((float2*)out)[(size_t)node * FD + lane] = o;
    }
}

// ---------------------------------------------------------------------------
extern "C" void kernel_launch(void* const* d_in, const int* in_sizes, int n_in,
                              void* d_out, int out_size, void* d_ws,
                              size_t ws_size, hipStream_t stream) {
    const float* x = (const float*)d_in[0];
    const int* ei = (const int*)d_in[1];
    const float* W1l = (const float*)d_in[2];
    const float* b1 = (const float*)d_in[3];
    const float* W1r = (const float*)d_in[4];
    const float* W2l = (const float*)d_in[5];
    const float* b2 = (const float*)d_in[6];
    const float* W2r = (const float*)d_in[7];
    float* out = (float*)d_out;

    const int n = in_sizes[0] / N_FEAT;  // 100000
    const int ne = in_sizes[1] / 2;      // 600000

    // ws: zl1|zr1 [n*64] | h [n*64] | zl2|zr2 [n*40] | wt1 | wt2 | ints
    unsigned short* zl1 = (unsigned short*)d_ws;
    unsigned short* zr1 = zl1 + (size_t)n * HID;
    unsigned short* h = zr1 + (size_t)n * HID;
    unsigned short* zl2 = h + (size_t)n * HID;
    unsigned short* zr2 = zl2 + (size_t)n * NCLS;
    unsigned short* wt1 = zr2 + (size_t)n * NCLS;
    unsigned short* wt2 = wt1 + 128 * 128;
    int* deg = (int*)(wt2 + 80 * 64);
    int* off = deg + n;
    int* rank = off + (n + 1);
    int* csr = rank + ne;
    int* bsums = csr + ne;
    int* flags = bsums + 256;

    const int nb = (n + 2047) / 2048;            // 49
    const int gblocks = (n + 63) / 64;           // 1563
    const int ablocks = (n + 3) / 4;
    const int pwork = (128 * 128 + 80 * 64 > n) ? (128 * 128 + 80 * 64) : n;

    // ---- weight prep + deg/flags zero ----
    prep_w<<<(pwork + 255) / 256, 256, 0, stream>>>(W1l, W1r, W2l, W2r, wt1,
                                                    wt2, deg, flags, n);

    // ---- layer-1 GEMM with distributed histogram ----
    gemm_l1_hist<<<gblocks, 256, 0, stream>>>(x, wt1, zl1, zr1, n, ei, deg,
                                              rank, ne);

    // ---- CSR offsets (single dispatch) + atomic-free fill ----
    scan_fused<<<nb, 256, 0, stream>>>(deg, off, n, bsums, flags);
    fill_csr<<<(ne + 255) / 256, 256, 0, stream>>>(ei, off, rank, csr, ne);

    // ---- layer 1 aggregate ----
    agg64_kernel<true>
        <<<ablocks, 256, 0, stream>>>(zl1, zr1, off, csr, b1, h, n);

    // ---- layer 2 ----
    gemm_mfma<HID, NCLS, false><<<gblocks, 256, 0, stream>>>(h, wt2, zl2, zr2, n);
    agg40_kernel<<<ablocks, 256, 0, stream>>>(zl2, zr2, off, csr, b2, out, n);
}

// Round 3
// 243.318 us; speedup vs baseline: 1.0349x; 1.0349x over previous
//
#include <hip/hip_runtime.h>
#include <hip/hip_bf16.h>

// GraphSAGE 2-layer forward — CSR-gather + bf16 MFMA GEMMs.
//   zl = x@W1l, zr = x@W1r     (bf16 MFMA, SPLIT packed arrays [n,64])
//   h  = sigmoid(csr_mean(zl) + zr + b1)        (h bf16 [n,64])
//   ql = h@W2l, qr = h@W2r     (split packed [n,40])
//   out = csr_mean(ql) + qr + b2                (fp32 [n,40])
//
// R3 changes vs 252µs:
//  - CSR build is now ATOMIC-FREE at global scope (R2 proved 600K device
//    atomics are a ~40µs memory-side RMW wall: WRITE_SIZE showed 600K x 32B).
//    New build: 2-level counting sort keyed on dst>>8 (391 buckets):
//      bucket_hist (LDS hist) -> lookback scan -> bucket_scatter (packed
//      edge, plain L2-absorbed stores) -> bucket_build (per-bucket LDS
//      sub-hist: writes off[] coalesced + csr reordered within ~6KB range).
//    Replaces hist-atomics AND fill_csr. gemm1 reverts to a pure GEMM.

#define N_FEAT 128
#define HID 64
#define NCLS 40
#define NE_BLK 1024

typedef short short8 __attribute__((ext_vector_type(8)));
typedef float floatx4 __attribute__((ext_vector_type(4)));

static __device__ __forceinline__ short f2bf(float x) {
    __hip_bfloat16 h = __float2bfloat16(x);
    return __builtin_bit_cast(short, h);
}
static __device__ __forceinline__ float bf2f(unsigned short u) {
    unsigned int v = ((unsigned int)u) << 16;
    return __builtin_bit_cast(float, v);
}

// ---------------------------------------------------------------------------
// Weight prep (transpose + cvt to bf16, concatenated [l|r]) + zero scan flags.
// ---------------------------------------------------------------------------
__global__ void prep_w(const float* __restrict__ W1l, const float* __restrict__ W1r,
                       const float* __restrict__ W2l, const float* __restrict__ W2r,
                       unsigned short* __restrict__ wt1,
                       unsigned short* __restrict__ wt2,
                       int* __restrict__ flags) {
    int i = blockIdx.x * blockDim.x + threadIdx.x;
    if (i < 128 * 128) {
        int nn = i >> 7, k = i & 127;
        float v = (nn < 64) ? W1l[k * 64 + nn] : W1r[k * 64 + (nn - 64)];
        wt1[nn * 128 + k] = (unsigned short)f2bf(v);
    } else if (i < 128 * 128 + 80 * 64) {
        int j = i - 128 * 128;
        int nn = j >> 6, k = j & 63;
        float v = (nn < 40) ? W2l[k * 40 + nn] : W2r[k * 40 + (nn - 40)];
        wt2[nn * 64 + k] = (unsigned short)f2bf(v);
    }
    if (i < 256) flags[i] = 0;
}

// ---------------------------------------------------------------------------
// Bucketed CSR build (no global atomics anywhere).
// Bucket key = dst >> 8  (nbuck = ceil(n/256) buckets of 256 nodes).
// ---------------------------------------------------------------------------
__global__ void bucket_hist(const int* __restrict__ ei, int ne, int n,
                            int* __restrict__ bh, int nbe) {
    __shared__ int bins[512];
    const int b = blockIdx.x, t = threadIdx.x;
    const int nbuck = (n + 255) >> 8;
    for (int i = t; i < nbuck; i += 256) bins[i] = 0;
    __syncthreads();
    const int e0 = b * NE_BLK;
    const int lim = (e0 + NE_BLK < ne) ? (e0 + NE_BLK) : ne;
    for (int e = e0 + t; e < lim; e += 256)
        atomicAdd(&bins[ei[ne + e] >> 8], 1);
    __syncthreads();
    for (int i = t; i < nbuck; i += 256) bh[i * nbe + b] = bins[i];
}

// Lookback exclusive scan: pre[0]=0, pre[i] = sum(in[0..i-1]); m up to ~500K.
__global__ void scan_fused(const int* __restrict__ in, int* __restrict__ pre,
                           int m, int* __restrict__ bsums,
                           int* __restrict__ flags) {
    __shared__ int lds[256];
    __shared__ int look[128];
    __shared__ int sprefix;
    const int b = blockIdx.x, t = threadIdx.x;
    const int base = b * 2048 + t * 8;
    int v[8], s = 0;
#pragma unroll
    for (int i = 0; i < 8; ++i) {
        int idx = base + i;
        v[i] = (idx < m) ? in[idx] : 0;
        s += v[i];
    }
    lds[t] = s;
    __syncthreads();
    for (int o = 1; o < 256; o <<= 1) {
        int y = (t >= o) ? lds[t - o] : 0;
        __syncthreads();
        lds[t] += y;
        __syncthreads();
    }
    if (t == 255) {
        __hip_atomic_store(&bsums[b], lds[255], __ATOMIC_RELEASE,
                           __HIP_MEMORY_SCOPE_AGENT);
        __hip_atomic_store(&flags[b], 1, __ATOMIC_RELEASE,
                           __HIP_MEMORY_SCOPE_AGENT);
    }
    if (t < 128) look[t] = 0;
    __syncthreads();
    if (t < b) {
        while (__hip_atomic_load(&flags[t], __ATOMIC_ACQUIRE,
                                 __HIP_MEMORY_SCOPE_AGENT) == 0) {}
        look[t] = __hip_atomic_load(&bsums[t], __ATOMIC_RELAXED,
                                    __HIP_MEMORY_SCOPE_AGENT);
    }
    __syncthreads();
    if (t == 0) {
        int p = 0;
        for (int i = 0; i < b; ++i) p += look[i];
        sprefix = p;
    }
    __syncthreads();
    int run = ((t == 0) ? 0 : lds[t - 1]) + sprefix;
#pragma unroll
    for (int i = 0; i < 8; ++i) {
        run += v[i];
        int idx = base + i;
        if (idx < m) pre[idx + 1] = run;
    }
    if (b == 0 && t == 0) pre[0] = 0;
}

// scatter edges into bucket-contiguous ebuf; packed (local_dst<<24)|src.
__global__ void bucket_scatter(const int* __restrict__ ei, int ne, int n,
                               const int* __restrict__ sbase,
                               int* __restrict__ ebuf, int nbe) {
    __shared__ int bins[512];
    const int b = blockIdx.x, t = threadIdx.x;
    const int nbuck = (n + 255) >> 8;
    for (int i = t; i < nbuck; i += 256) bins[i] = 0;
    __syncthreads();
    const int e0 = b * NE_BLK;
    const int lim = (e0 + NE_BLK < ne) ? (e0 + NE_BLK) : ne;
    for (int e = e0 + t; e < lim; e += 256) {
        int d = ei[ne + e];
        int s = ei[e];
        int bk = d >> 8;
        int r = atomicAdd(&bins[bk], 1);
        int p = sbase[bk * nbe + b] + r;
        ebuf[p] = (int)(((unsigned)(d & 255) << 24) | (unsigned)s);
    }
}

// one block per bucket: LDS 256-bin sub-histogram + scan -> off[] (coalesced)
// and csr reordered within the bucket's contiguous range.
__global__ void bucket_build(const int* __restrict__ ebuf,
                             const int* __restrict__ sbase, int nbe, int n,
                             int ne, int* __restrict__ off,
                             int* __restrict__ csr) {
    __shared__ int cnt[256];
    __shared__ int sc[256];
    __shared__ int pos[256];
    const int b = blockIdx.x;
    const int t = threadIdx.x;
    const int nbuck = (n + 255) >> 8;
    const int s0 = sbase[b * nbe];
    const int s1 = (b + 1 < nbuck) ? sbase[(b + 1) * nbe] : ne;
    cnt[t] = 0;
    __syncthreads();
    for (int i = s0 + t; i < s1; i += 256)
        atomicAdd(&cnt[((unsigned)ebuf[i]) >> 24], 1);
    __syncthreads();
    int v = cnt[t];
    sc[t] = v;
    __syncthreads();
    for (int o = 1; o < 256; o <<= 1) {
        int y = (t >= o) ? sc[t - o] : 0;
        __syncthreads();
        sc[t] += y;
        __syncthreads();
    }
    int g = b * 256 + t;
    if (g < n) off[g + 1] = s0 + sc[t];
    if (b == 0 && t == 0) off[0] = 0;
    pos[t] = s0 + sc[t] - v;  // exclusive
    __syncthreads();
    for (int i = s0 + t; i < s1; i += 256) {
        unsigned w = (unsigned)ebuf[i];
        int p = atomicAdd(&pos[w >> 24], 1);
        csr[p] = (int)(w & 0xFFFFFFu);
    }
}

// ---------------------------------------------------------------------------
// MFMA GEMM: cols [0,MH) -> Zl packed [n,MH], cols [MH,2MH) -> Zr [n,MH].
// Block = 256 thr (4 waves), 64 rows/block; K fully staged in LDS (+8 pad).
// ---------------------------------------------------------------------------
template <int K, int MH, bool AF32>
__global__ __launch_bounds__(256) void gemm_mfma(
    const void* __restrict__ Ain, const unsigned short* __restrict__ Wt,
    unsigned short* __restrict__ Zl, unsigned short* __restrict__ Zr, int n) {
    constexpr int M = 2 * MH;
    constexpr int LDA = K + 8;
    constexpr int MT = (M + 15) / 16;
    constexpr int KS = K / 32;
    constexpr int QROW = K / 8;
    __shared__ __align__(16) short At[64 * LDA];
    __shared__ __align__(16) short Bt[M * LDA];

    const int t = threadIdx.x;
    const int nodeBase = blockIdx.x * 64;

    for (int q = t; q < 64 * QROW; q += 256) {
        int row = q / QROW;
        int k0 = (q % QROW) * 8;
        int node = nodeBase + row;
        short8 s = {0, 0, 0, 0, 0, 0, 0, 0};
        if (node < n) {
            if (AF32) {
                const float* A = (const float*)Ain + (size_t)node * K + k0;
                float4 v0 = *(const float4*)A;
                float4 v1 = *(const float4*)(A + 4);
                s[0] = f2bf(v0.x); s[1] = f2bf(v0.y);
                s[2] = f2bf(v0.z); s[3] = f2bf(v0.w);
                s[4] = f2bf(v1.x); s[5] = f2bf(v1.y);
                s[6] = f2bf(v1.z); s[7] = f2bf(v1.w);
            } else {
                s = *(const short8*)((const short*)Ain + (size_t)node * K + k0);
            }
        }
        *(short8*)&At[row * LDA + k0] = s;
    }
    for (int q = t; q < M * QROW; q += 256) {
        int row = q / QROW;
        int k0 = (q % QROW) * 8;
        *(short8*)&Bt[row * LDA + k0] =
            *(const short8*)((const short*)Wt + (size_t)row * K + k0);
    }
    __syncthreads();

    const int wave = t >> 6;
    const int lane = t & 63;
    const int m0 = wave * 16;
    const int fl = lane & 15;
    const int quad = lane >> 4;

    floatx4 acc[MT];
#pragma unroll
    for (int nt = 0; nt < MT; ++nt) acc[nt] = (floatx4){0.f, 0.f, 0.f, 0.f};

#pragma unroll
    for (int ks = 0; ks < KS; ++ks) {
        const int kb = ks * 32 + quad * 8;
        short8 a = *(const short8*)&At[(m0 + fl) * LDA + kb];
#pragma unroll
        for (int nt = 0; nt < MT; ++nt) {
            short8 b = *(const short8*)&Bt[(nt * 16 + fl) * LDA + kb];
            acc[nt] = __builtin_amdgcn_mfma_f32_16x16x32_bf16(a, b, acc[nt], 0, 0, 0);
        }
    }

    // epilogue: D[row=quad*4+r][col=nt*16+fl] -> split Zl/Zr (packed MH)
#pragma unroll
    for (int nt = 0; nt < MT; ++nt) {
        const int col = nt * 16 + fl;
#pragma unroll
        for (int r = 0; r < 4; ++r) {
            int node = nodeBase + m0 + quad * 4 + r;
            if (node < n) {
                unsigned short v = (unsigned short)f2bf(acc[nt][r]);
                if (col < MH)
                    Zl[(size_t)node * MH + col] = v;
                else
                    Zr[(size_t)node * MH + (col - MH)] = v;
            }
        }
    }
}

// ---------------------------------------------------------------------------
// CSR aggregate, F=64: one wave per node; 8 lanes x dwordx4 = one 128B row,
// so 8 edges are gathered per load instruction. shfl_xor(8/16/32) combine.
// ---------------------------------------------------------------------------
template <bool SIG>
__global__ void agg64_kernel(const unsigned short* __restrict__ Zl,
                             const unsigned short* __restrict__ Zr,
                             const int* __restrict__ off,
                             const int* __restrict__ csr,
                             const float* __restrict__ bias,
                             void* __restrict__ out, int n) {
    const int node = blockIdx.x * (blockDim.x >> 6) + (threadIdx.x >> 6);
    if (node >= n) return;
    const int lane = threadIdx.x & 63;
    const int start = off[node];
    const int end = off[node + 1];
    const int g = lane >> 3;   // edge slot 0..7
    const int c = lane & 7;    // 16B chunk: feats [8c, 8c+8)

    float a0 = 0.f, a1 = 0.f, a2 = 0.f, a3 = 0.f;
    float a4 = 0.f, a5 = 0.f, a6 = 0.f, a7 = 0.f;
    for (int e = start; e < end; e += 8) {
        int ee = e + g;
        int idx = csr[(ee < end) ? ee : (end - 1)];
        float w = (ee < end) ? 1.f : 0.f;
        uint4 d = *(const uint4*)(Zl + (size_t)idx * 64 + c * 8);
        a0 = fmaf(w, bf2f((unsigned short)(d.x & 0xffffu)), a0);
        a1 = fmaf(w, bf2f((unsigned short)(d.x >> 16)), a1);
        a2 = fmaf(w, bf2f((unsigned short)(d.y & 0xffffu)), a2);
        a3 = fmaf(w, bf2f((unsigned short)(d.y >> 16)), a3);
        a4 = fmaf(w, bf2f((unsigned short)(d.z & 0xffffu)), a4);
        a5 = fmaf(w, bf2f((unsigned short)(d.z >> 16)), a5);
        a6 = fmaf(w, bf2f((unsigned short)(d.w & 0xffffu)), a6);
        a7 = fmaf(w, bf2f((unsigned short)(d.w >> 16)), a7);
    }
#pragma unroll
    for (int o = 8; o < 64; o <<= 1) {
        a0 += __shfl_xor(a0, o); a1 += __shfl_xor(a1, o);
        a2 += __shfl_xor(a2, o); a3 += __shfl_xor(a3, o);
        a4 += __shfl_xor(a4, o); a5 += __shfl_xor(a5, o);
        a6 += __shfl_xor(a6, o); a7 += __shfl_xor(a7, o);
    }
    if (g == 0) {
        float inv = 1.0f / fmaxf((float)(end - start), 1.0f);
        uint4 z = *(const uint4*)(Zr + (size_t)node * 64 + c * 8);
        float4 b0 = ((const float4*)bias)[c * 2];
        float4 b1 = ((const float4*)bias)[c * 2 + 1];
        float r0 = a0 * inv + bf2f((unsigned short)(z.x & 0xffffu)) + b0.x;
        float r1 = a1 * inv + bf2f((unsigned short)(z.x >> 16)) + b0.y;
        float r2 = a2 * inv + bf2f((unsigned short)(z.y & 0xffffu)) + b0.z;
        float r3 = a3 * inv + bf2f((unsigned short)(z.y >> 16)) + b0.w;
        float r4 = a4 * inv + bf2f((unsigned short)(z.z & 0xffffu)) + b1.x;
        float r5 = a5 * inv + bf2f((unsigned short)(z.z >> 16)) + b1.y;
        float r6 = a6 * inv + bf2f((unsigned short)(z.w & 0xffffu)) + b1.z;
        float r7 = a7 * inv + bf2f((unsigned short)(z.w >> 16)) + b1.w;
        if (SIG) {
            r0 = 1.0f / (1.0f + __expf(-r0));
            r1 = 1.0f / (1.0f + __expf(-r1));
            r2 = 1.0f / (1.0f + __expf(-r2));
            r3 = 1.0f / (1.0f + __expf(-r3));
            r4 = 1.0f / (1.0f + __expf(-r4));
            r5 = 1.0f / (1.0f + __expf(-r5));
            r6 = 1.0f / (1.0f + __expf(-r6));
            r7 = 1.0f / (1.0f + __expf(-r7));
        }
        uint4 p;
        p.x = (unsigned int)(unsigned short)f2bf(r0) |
              ((unsigned int)(unsigned short)f2bf(r1) << 16);
        p.y = (unsigned int)(unsigned short)f2bf(r2) |
              ((unsigned int)(unsigned short)f2bf(r3) << 16);
        p.z = (unsigned int)(unsigned short)f2bf(r4) |
              ((unsigned int)(unsigned short)f2bf(r5) << 16);
        p.w = (unsigned int)(unsigned short)f2bf(r6) |
              ((unsigned int)(unsigned short)f2bf(r7) << 16);
        *(uint4*)((unsigned short*)out + (size_t)node * 64 + c * 8) = p;
    }
}

// ---------------------------------------------------------------------------
// CSR aggregate, F=40 (layer 2): dword gathers, 2 edges per load, fp32 out.
// ---------------------------------------------------------------------------
__global__ void agg40_kernel(const unsigned short* __restrict__ Zl,
                             const unsigned short* __restrict__ Zr,
                             const int* __restrict__ off,
                             const int* __restrict__ csr,
                             const float* __restrict__ bias,
                             float* __restrict__ out, int n) {
    constexpr int F = NCLS;
    constexpr int FD = F / 2;  // 20 dwords per row
    const int node = blockIdx.x * (blockDim.x >> 6) + (threadIdx.x >> 6);
    if (node >= n) return;
    const int lane = threadIdx.x & 63;
    const int start = off[node];
    const int end = off[node + 1];
    const int half = lane >> 5;
    const int col = lane & 31;
    float ax = 0.f, ay = 0.f;
    for (int e = start; e < end; e += 8) {
        int idx[8];
#pragma unroll
        for (int i = 0; i < 8; ++i) {
            int ee = (e + i < end) ? (e + i) : (end - 1);
            idx[i] = csr[ee];
        }
#pragma unroll
        for (int i = 0; i < 4; ++i) {
            unsigned int d = 0;
            if (col < FD)
                d = *(const unsigned int*)(Zl + (size_t)idx[2 * i + half] * F +
                                           2 * col);
            float w = (e + 2 * i + half < end) ? 1.f : 0.f;
            ax += w * bf2f((unsigned short)(d & 0xffffu));
            ay += w * bf2f((unsigned short)(d >> 16));
        }
    }
    ax += __shfl_xor(ax, 32);
    ay += __shfl_xor(ay, 32);
    if (lane < FD) {
        float inv = 1.0f / fmaxf((float)(end - start), 1.0f);
        unsigned int z =
            *(const unsigned int*)(Zr + (size_t)node * F + 2 * lane);
        float2 bb = ((const float2*)bias)[lane];
        float rx = ax * inv + bf2f((unsigned short)(z & 0xffffu)) + bb.x;
        float ry = ay * inv + bf2f((unsigned short)(z >> 16)) + bb.y;
        float2 o = {rx, ry};
        ((float2*)out)[(size_t)node * FD + lane] = o;
    }
}

// ---------------------------------------------------------------------------
extern "C" void kernel_launch(void* const* d_in, const int* in_sizes, int n_in,
                              void* d_out, int out_size, void* d_ws,
                              size_t ws_size, hipStream_t stream) {
    const float* x = (const float*)d_in[0];
    const int* ei = (const int*)d_in[1];
    const float* W1l = (const float*)d_in[2];
    const float* b1 = (const float*)d_in[3];
    const float* W1r = (const float*)d_in[4];
    const float* W2l = (const float*)d_in[5];
    const float* b2 = (const float*)d_in[6];
    const float* W2r = (const float*)d_in[7];
    float* out = (float*)d_out;

    const int n = in_sizes[0] / N_FEAT;  // 100000
    const int ne = in_sizes[1] / 2;      // 600000

    const int nbe = (ne + NE_BLK - 1) / NE_BLK;   // 586 edge blocks
    const int nbuck = (n + 255) >> 8;             // 391 buckets
    const int tot = nbuck * nbe;                  // count-matrix size

    // ws layout
    unsigned short* zl1 = (unsigned short*)d_ws;
    unsigned short* zr1 = zl1 + (size_t)n * HID;
    unsigned short* h = zr1 + (size_t)n * HID;
    unsigned short* zl2 = h + (size_t)n * HID;
    unsigned short* zr2 = zl2 + (size_t)n * NCLS;
    unsigned short* wt1 = zr2 + (size_t)n * NCLS;
    unsigned short* wt2 = wt1 + 128 * 128;
    int* off = (int*)(wt2 + 80 * 64);
    int* csr = off + (n + 1);
    int* ebuf = csr + ne;
    int* bh = ebuf + ne;
    int* sbase = bh + tot;
    int* bsums = sbase + (tot + 1);
    int* flags = bsums + 256;

    const int gblocks = (n + 63) / 64;
    const int ablocks = (n + 3) / 4;
    const int nsb = (tot + 2047) / 2048;  // scan blocks (~112)

    // ---- weight prep + scan-flag zero ----
    prep_w<<<(128 * 128 + 80 * 64 + 255) / 256, 256, 0, stream>>>(
        W1l, W1r, W2l, W2r, wt1, wt2, flags);

    // ---- layer-1 GEMM (pure) ----
    gemm_mfma<N_FEAT, HID, true><<<gblocks, 256, 0, stream>>>(x, wt1, zl1, zr1, n);

    // ---- atomic-free CSR build ----
    bucket_hist<<<nbe, 256, 0, stream>>>(ei, ne, n, bh, nbe);
    scan_fused<<<nsb, 256, 0, stream>>>(bh, sbase, tot, bsums, flags);
    bucket_scatter<<<nbe, 256, 0, stream>>>(ei, ne, n, sbase, ebuf, nbe);
    bucket_build<<<nbuck, 256, 0, stream>>>(ebuf, sbase, nbe, n, ne, off, csr);

    // ---- layer 1 aggregate ----
    agg64_kernel<true>
        <<<ablocks, 256, 0, stream>>>(zl1, zr1, off, csr, b1, h, n);

    // ---- layer 2 ----
    gemm_mfma<HID, NCLS, false><<<gblocks, 256, 0, stream>>>(h, wt2, zl2, zr2, n);
    agg40_kernel<<<ablocks, 256, 0, stream>>>(zl2, zr2, off, csr, b2, out, n);
}

// Round 4
// 217.967 us; speedup vs baseline: 1.1552x; 1.1163x over previous
//
#include <hip/hip_runtime.h>
#include <hip/hip_bf16.h>

// GraphSAGE 2-layer forward — CSR-gather + bf16 MFMA GEMMs.
//   zl = x@W1l, zr = x@W1r      (bf16 MFMA, SPLIT packed arrays [n,64])
//   h  = sigmoid(csr_mean(zl) + zr + b1)        (h bf16 [n,64])
//   aggh = csr_mean(h)                          (bf16 [n,64])
//   out = [aggh | h] @ [W2l;W2r] + b2           (K=128 cat-GEMM, fp32 out)
//
// R4 changes vs 243µs:
//  - Layer-2 restructured via linearity of mean-aggregation:
//    mean(h)@W2l + h@W2r == [mean(h)|h] @ [W2l;W2r].  Deletes agg40 (was 47µs,
//    VALUBusy 62%) and the zl2/zr2 round trip; adds agg_h (clean 128B-row
//    gather) + one K=128 GEMM writing fp32 out directly with bias.
//  - Aggregators: 2 nodes per wave (2 independent memory chains/wave), csr
//    indices preloaded once per node (64 ranks) and distributed via __shfl —
//    gathers for all iterations issue back-to-back after one csr load.
//  - bucket_hist fused into prep_w; NE_BLK=2048 (halves count matrix).

#define N_FEAT 128
#define HID 64
#define NCLS 40
#define NE_BLK 2048

typedef short short8 __attribute__((ext_vector_type(8)));
typedef float floatx4 __attribute__((ext_vector_type(4)));

static __device__ __forceinline__ short f2bf(float x) {
    __hip_bfloat16 h = __float2bfloat16(x);
    return __builtin_bit_cast(short, h);
}
static __device__ __forceinline__ float bf2f(unsigned short u) {
    unsigned int v = ((unsigned int)u) << 16;
    return __builtin_bit_cast(float, v);
}

// ---------------------------------------------------------------------------
// Weight prep (wt1 [128][128], wt2cat [48][128] = [W2l;W2r]^T padded) +
// bucket histogram (LDS bins, key = dst>>8) + scan-flag zero. One dispatch.
// ---------------------------------------------------------------------------
__global__ void prep_hist(const float* __restrict__ W1l, const float* __restrict__ W1r,
                          const float* __restrict__ W2l, const float* __restrict__ W2r,
                          unsigned short* __restrict__ wt1,
                          unsigned short* __restrict__ wt2,
                          int* __restrict__ flags,
                          const int* __restrict__ ei, int ne, int n,
                          int* __restrict__ bh, int nbe) {
    __shared__ int bins[512];
    const int b = blockIdx.x, t = threadIdx.x;
    const int nbuck = (n + 255) >> 8;
    for (int i = t; i < nbuck; i += 256) bins[i] = 0;
    __syncthreads();
    const int e0 = b * NE_BLK;
    const int lim = (e0 + NE_BLK < ne) ? (e0 + NE_BLK) : ne;
    for (int e = e0 + t; e < lim; e += 256)
        atomicAdd(&bins[ei[ne + e] >> 8], 1);

    int i = b * 256 + t;
    if (i < 128 * 128) {
        int nn = i >> 7, k = i & 127;
        float v = (nn < 64) ? W1l[k * 64 + nn] : W1r[k * 64 + (nn - 64)];
        wt1[nn * 128 + k] = (unsigned short)f2bf(v);
    } else if (i < 128 * 128 + 48 * 128) {
        int j = i - 128 * 128;
        int nn = j >> 7, k = j & 127;
        float v = 0.f;
        if (nn < 40)
            v = (k < 64) ? W2l[k * 40 + nn] : W2r[(k - 64) * 40 + nn];
        wt2[nn * 128 + k] = (unsigned short)f2bf(v);
    }
    if (i < 256) flags[i] = 0;

    __syncthreads();
    for (int j = t; j < nbuck; j += 256) bh[j * nbe + b] = bins[j];
}

// ---------------------------------------------------------------------------
// Lookback exclusive scan: pre[0]=0, pre[i]=sum(in[0..i-1]).
// ---------------------------------------------------------------------------
__global__ void scan_fused(const int* __restrict__ in, int* __restrict__ pre,
                           int m, int* __restrict__ bsums,
                           int* __restrict__ flags) {
    __shared__ int lds[256];
    __shared__ int look[128];
    __shared__ int sprefix;
    const int b = blockIdx.x, t = threadIdx.x;
    const int base = b * 2048 + t * 8;
    int v[8], s = 0;
#pragma unroll
    for (int i = 0; i < 8; ++i) {
        int idx = base + i;
        v[i] = (idx < m) ? in[idx] : 0;
        s += v[i];
    }
    lds[t] = s;
    __syncthreads();
    for (int o = 1; o < 256; o <<= 1) {
        int y = (t >= o) ? lds[t - o] : 0;
        __syncthreads();
        lds[t] += y;
        __syncthreads();
    }
    if (t == 255) {
        __hip_atomic_store(&bsums[b], lds[255], __ATOMIC_RELEASE,
                           __HIP_MEMORY_SCOPE_AGENT);
        __hip_atomic_store(&flags[b], 1, __ATOMIC_RELEASE,
                           __HIP_MEMORY_SCOPE_AGENT);
    }
    if (t < 128) look[t] = 0;
    __syncthreads();
    if (t < b) {
        while (__hip_atomic_load(&flags[t], __ATOMIC_ACQUIRE,
                                 __HIP_MEMORY_SCOPE_AGENT) == 0) {}
        look[t] = __hip_atomic_load(&bsums[t], __ATOMIC_RELAXED,
                                    __HIP_MEMORY_SCOPE_AGENT);
    }
    __syncthreads();
    if (t == 0) {
        int p = 0;
        for (int i = 0; i < b; ++i) p += look[i];
        sprefix = p;
    }
    __syncthreads();
    int run = ((t == 0) ? 0 : lds[t - 1]) + sprefix;
#pragma unroll
    for (int i = 0; i < 8; ++i) {
        run += v[i];
        int idx = base + i;
        if (idx < m) pre[idx + 1] = run;
    }
    if (b == 0 && t == 0) pre[0] = 0;
}

// scatter edges into bucket-contiguous ebuf; packed (local_dst<<24)|src.
__global__ void bucket_scatter(const int* __restrict__ ei, int ne, int n,
                               const int* __restrict__ sbase,
                               int* __restrict__ ebuf, int nbe) {
    __shared__ int bins[512];
    const int b = blockIdx.x, t = threadIdx.x;
    const int nbuck = (n + 255) >> 8;
    for (int i = t; i < nbuck; i += 256) bins[i] = 0;
    __syncthreads();
    const int e0 = b * NE_BLK;
    const int lim = (e0 + NE_BLK < ne) ? (e0 + NE_BLK) : ne;
    for (int e = e0 + t; e < lim; e += 256) {
        int d = ei[ne + e];
        int s = ei[e];
        int bk = d >> 8;
        int r = atomicAdd(&bins[bk], 1);
        int p = sbase[bk * nbe + b] + r;
        ebuf[p] = (int)(((unsigned)(d & 255) << 24) | (unsigned)s);
    }
}

// one block per bucket: LDS 256-bin sub-histogram + scan -> off[] (coalesced)
// and csr reordered within the bucket's contiguous range.
__global__ void bucket_build(const int* __restrict__ ebuf,
                             const int* __restrict__ sbase, int nbe, int n,
                             int ne, int* __restrict__ off,
                             int* __restrict__ csr) {
    __shared__ int cnt[256];
    __shared__ int sc[256];
    __shared__ int pos[256];
    const int b = blockIdx.x;
    const int t = threadIdx.x;
    const int nbuck = (n + 255) >> 8;
    const int s0 = sbase[b * nbe];
    const int s1 = (b + 1 < nbuck) ? sbase[(b + 1) * nbe] : ne;
    cnt[t] = 0;
    __syncthreads();
    for (int i = s0 + t; i < s1; i += 256)
        atomicAdd(&cnt[((unsigned)ebuf[i]) >> 24], 1);
    __syncthreads();
    int v = cnt[t];
    sc[t] = v;
    __syncthreads();
    for (int o = 1; o < 256; o <<= 1) {
        int y = (t >= o) ? sc[t - o] : 0;
        __syncthreads();
        sc[t] += y;
        __syncthreads();
    }
    int g = b * 256 + t;
    if (g < n) off[g + 1] = s0 + sc[t];
    if (b == 0 && t == 0) off[0] = 0;
    pos[t] = s0 + sc[t] - v;  // exclusive
    __syncthreads();
    for (int i = s0 + t; i < s1; i += 256) {
        unsigned w = (unsigned)ebuf[i];
        int p = atomicAdd(&pos[w >> 24], 1);
        csr[p] = (int)(w & 0xFFFFFFu);
    }
}

// ---------------------------------------------------------------------------
// Layer-1 MFMA GEMM: cols [0,64) -> Zl, [64,128) -> Zr (both packed [n,64]).
// ---------------------------------------------------------------------------
template <int K, int MH, bool AF32>
__global__ __launch_bounds__(256) void gemm_mfma(
    const void* __restrict__ Ain, const unsigned short* __restrict__ Wt,
    unsigned short* __restrict__ Zl, unsigned short* __restrict__ Zr, int n) {
    constexpr int M = 2 * MH;
    constexpr int LDA = K + 8;
    constexpr int MT = (M + 15) / 16;
    constexpr int KS = K / 32;
    constexpr int QROW = K / 8;
    __shared__ __align__(16) short At[64 * LDA];
    __shared__ __align__(16) short Bt[M * LDA];

    const int t = threadIdx.x;
    const int nodeBase = blockIdx.x * 64;

    for (int q = t; q < 64 * QROW; q += 256) {
        int row = q / QROW;
        int k0 = (q % QROW) * 8;
        int node = nodeBase + row;
        short8 s = {0, 0, 0, 0, 0, 0, 0, 0};
        if (node < n) {
            if (AF32) {
                const float* A = (const float*)Ain + (size_t)node * K + k0;
                float4 v0 = *(const float4*)A;
                float4 v1 = *(const float4*)(A + 4);
                s[0] = f2bf(v0.x); s[1] = f2bf(v0.y);
                s[2] = f2bf(v0.z); s[3] = f2bf(v0.w);
                s[4] = f2bf(v1.x); s[5] = f2bf(v1.y);
                s[6] = f2bf(v1.z); s[7] = f2bf(v1.w);
            } else {
                s = *(const short8*)((const short*)Ain + (size_t)node * K + k0);
            }
        }
        *(short8*)&At[row * LDA + k0] = s;
    }
    for (int q = t; q < M * QROW; q += 256) {
        int row = q / QROW;
        int k0 = (q % QROW) * 8;
        *(short8*)&Bt[row * LDA + k0] =
            *(const short8*)((const short*)Wt + (size_t)row * K + k0);
    }
    __syncthreads();

    const int wave = t >> 6;
    const int lane = t & 63;
    const int m0 = wave * 16;
    const int fl = lane & 15;
    const int quad = lane >> 4;

    floatx4 acc[MT];
#pragma unroll
    for (int nt = 0; nt < MT; ++nt) acc[nt] = (floatx4){0.f, 0.f, 0.f, 0.f};

#pragma unroll
    for (int ks = 0; ks < KS; ++ks) {
        const int kb = ks * 32 + quad * 8;
        short8 a = *(const short8*)&At[(m0 + fl) * LDA + kb];
#pragma unroll
        for (int nt = 0; nt < MT; ++nt) {
            short8 b = *(const short8*)&Bt[(nt * 16 + fl) * LDA + kb];
            acc[nt] = __builtin_amdgcn_mfma_f32_16x16x32_bf16(a, b, acc[nt], 0, 0, 0);
        }
    }

#pragma unroll
    for (int nt = 0; nt < MT; ++nt) {
        const int col = nt * 16 + fl;
#pragma unroll
        for (int r = 0; r < 4; ++r) {
            int node = nodeBase + m0 + quad * 4 + r;
            if (node < n) {
                unsigned short v = (unsigned short)f2bf(acc[nt][r]);
                if (col < MH)
                    Zl[(size_t)node * MH + col] = v;
                else
                    Zr[(size_t)node * MH + (col - MH)] = v;
            }
        }
    }
}

// ---------------------------------------------------------------------------
// Layer-2 cat-GEMM: A = [aggh | h] (K=128), B = wt2cat [48][128],
// out = A@B + b2 written fp32 [n,40] directly.
// ---------------------------------------------------------------------------
__global__ __launch_bounds__(256) void gemm2cat(
    const unsigned short* __restrict__ aggh, const unsigned short* __restrict__ h,
    const unsigned short* __restrict__ Wt, const float* __restrict__ bias,
    float* __restrict__ out, int n) {
    constexpr int K = 128;
    constexpr int LDA = K + 8;
    constexpr int M = 48;
    constexpr int MT = 3;
    __shared__ __align__(16) short At[64 * LDA];
    __shared__ __align__(16) short Bt[M * LDA];

    const int t = threadIdx.x;
    const int nodeBase = blockIdx.x * 64;

    for (int q = t; q < 64 * 16; q += 256) {
        int row = q >> 4;
        int k0 = (q & 15) * 8;
        int node = nodeBase + row;
        short8 s = {0, 0, 0, 0, 0, 0, 0, 0};
        if (node < n) {
            const unsigned short* src =
                (k0 < 64) ? (aggh + (size_t)node * 64 + k0)
                          : (h + (size_t)node * 64 + (k0 - 64));
            s = *(const short8*)src;
        }
        *(short8*)&At[row * LDA + k0] = s;
    }
    for (int q = t; q < M * 16; q += 256) {
        int row = q >> 4;
        int k0 = (q & 15) * 8;
        *(short8*)&Bt[row * LDA + k0] =
            *(const short8*)((const short*)Wt + (size_t)row * K + k0);
    }
    __syncthreads();

    const int wave = t >> 6;
    const int lane = t & 63;
    const int m0 = wave * 16;
    const int fl = lane & 15;
    const int quad = lane >> 4;

    floatx4 acc[MT];
#pragma unroll
    for (int nt = 0; nt < MT; ++nt) acc[nt] = (floatx4){0.f, 0.f, 0.f, 0.f};

#pragma unroll
    for (int ks = 0; ks < 4; ++ks) {
        const int kb = ks * 32 + quad * 8;
        short8 a = *(const short8*)&At[(m0 + fl) * LDA + kb];
#pragma unroll
        for (int nt = 0; nt < MT; ++nt) {
            short8 b = *(const short8*)&Bt[(nt * 16 + fl) * LDA + kb];
            acc[nt] = __builtin_amdgcn_mfma_f32_16x16x32_bf16(a, b, acc[nt], 0, 0, 0);
        }
    }

#pragma unroll
    for (int nt = 0; nt < MT; ++nt) {
        const int col = nt * 16 + fl;
        if (col < NCLS) {
            float bv = bias[col];
#pragma unroll
            for (int r = 0; r < 4; ++r) {
                int node = nodeBase + m0 + quad * 4 + r;
                if (node < n)
                    out[(size_t)node * NCLS + col] = acc[nt][r] + bv;
            }
        }
    }
}

// ---------------------------------------------------------------------------
// CSR mean-aggregate over 128B bf16 rows; 2 nodes per wave (2 independent
// memory chains). Per node: csr ranks preloaded once (<=64) and distributed
// via __shfl; 8 edge slots x 8 dwordx4 chunks per gather round.
// MODE 0: h = sigmoid(mean + Zr + bias) -> bf16.   MODE 1: mean -> bf16.
// ---------------------------------------------------------------------------
template <int MODE>
__global__ void agg64_kernel(const unsigned short* __restrict__ Zl,
                             const unsigned short* __restrict__ Zr,
                             const int* __restrict__ off,
                             const int* __restrict__ csr,
                             const float* __restrict__ bias,
                             unsigned short* __restrict__ out, int n) {
    const int wid = blockIdx.x * (blockDim.x >> 6) + (threadIdx.x >> 6);
    const int node0 = wid * 2;
    if (node0 >= n) return;
    const int lane = threadIdx.x & 63;
    const int g = lane >> 3;   // edge slot 0..7
    const int c = lane & 7;    // 16B chunk

    const bool has1 = (node0 + 1) < n;
    const int s0 = off[node0];
    const int e0 = off[node0 + 1];
    const int e1 = has1 ? off[node0 + 2] : e0;
    const int d0 = e0 - s0;
    const int d1 = e1 - e0;

    int ed0 = (d0 > 0) ? csr[s0 + ((lane < d0) ? lane : (d0 - 1))] : 0;
    int ed1 = (d1 > 0) ? csr[e0 + ((lane < d1) ? lane : (d1 - 1))] : 0;

    float a0[8], a1[8];
#pragma unroll
    for (int j = 0; j < 8; ++j) { a0[j] = 0.f; a1[j] = 0.f; }

    const int dm = (d0 > d1) ? d0 : d1;
    for (int e = 0; e < dm; e += 8) {
        const int r = e + g;
        int i0, i1;
        if (e < 64) {  // wave-uniform branch
            i0 = __shfl(ed0, (r < d0) ? r : ((d0 > 0) ? d0 - 1 : 0));
            i1 = __shfl(ed1, (r < d1) ? r : ((d1 > 0) ? d1 - 1 : 0));
        } else {       // deg > 64 fallback (rare)
            i0 = (d0 > 0) ? csr[s0 + ((r < d0) ? r : d0 - 1)] : 0;
            i1 = (d1 > 0) ? csr[e0 + ((r < d1) ? r : d1 - 1)] : 0;
        }
        const float w0 = (r < d0) ? 1.f : 0.f;
        const float w1 = (r < d1) ? 1.f : 0.f;
        uint4 v0 = *(const uint4*)(Zl + (size_t)i0 * 64 + c * 8);
        uint4 v1 = *(const uint4*)(Zl + (size_t)i1 * 64 + c * 8);
        a0[0] = fmaf(w0, bf2f((unsigned short)(v0.x & 0xffffu)), a0[0]);
        a0[1] = fmaf(w0, bf2f((unsigned short)(v0.x >> 16)), a0[1]);
        a0[2] = fmaf(w0, bf2f((unsigned short)(v0.y & 0xffffu)), a0[2]);
        a0[3] = fmaf(w0, bf2f((unsigned short)(v0.y >> 16)), a0[3]);
        a0[4] = fmaf(w0, bf2f((unsigned short)(v0.z & 0xffffu)), a0[4]);
        a0[5] = fmaf(w0, bf2f((unsigned short)(v0.z >> 16)), a0[5]);
        a0[6] = fmaf(w0, bf2f((unsigned short)(v0.w & 0xffffu)), a0[6]);
        a0[7] = fmaf(w0, bf2f((unsigned short)(v0.w >> 16)), a0[7]);
        a1[0] = fmaf(w1, bf2f((unsigned short)(v1.x & 0xffffu)), a1[0]);
        a1[1] = fmaf(w1, bf2f((unsigned short)(v1.x >> 16)), a1[1]);
        a1[2] = fmaf(w1, bf2f((unsigned short)(v1.y & 0xffffu)), a1[2]);
        a1[3] = fmaf(w1, bf2f((unsigned short)(v1.y >> 16)), a1[3]);
        a1[4] = fmaf(w1, bf2f((unsigned short)(v1.z & 0xffffu)), a1[4]);
        a1[5] = fmaf(w1, bf2f((unsigned short)(v1.z >> 16)), a1[5]);
        a1[6] = fmaf(w1, bf2f((unsigned short)(v1.w & 0xffffu)), a1[6]);
        a1[7] = fmaf(w1, bf2f((unsigned short)(v1.w >> 16)), a1[7]);
    }
#pragma unroll
    for (int o = 8; o < 64; o <<= 1) {
#pragma unroll
        for (int j = 0; j < 8; ++j) {
            a0[j] += __shfl_xor(a0[j], o);
            a1[j] += __shfl_xor(a1[j], o);
        }
    }
    if (g < 2) {
        const int node = node0 + g;
        if (node < n) {
            const int dd = g ? d1 : d0;
            float rr[8];
#pragma unroll
            for (int j = 0; j < 8; ++j) rr[j] = g ? a1[j] : a0[j];
            const float inv = 1.0f / fmaxf((float)dd, 1.0f);
            float r0, r1, r2, r3, r4, r5, r6, r7;
            if (MODE == 0) {
                uint4 z = *(const uint4*)(Zr + (size_t)node * 64 + c * 8);
                float4 b0 = ((const float4*)bias)[c * 2];
                float4 b1 = ((const float4*)bias)[c * 2 + 1];
                r0 = rr[0] * inv + bf2f((unsigned short)(z.x & 0xffffu)) + b0.x;
                r1 = rr[1] * inv + bf2f((unsigned short)(z.x >> 16)) + b0.y;
                r2 = rr[2] * inv + bf2f((unsigned short)(z.y & 0xffffu)) + b0.z;
                r3 = rr[3] * inv + bf2f((unsigned short)(z.y >> 16)) + b0.w;
                r4 = rr[4] * inv + bf2f((unsigned short)(z.z & 0xffffu)) + b1.x;
                r5 = rr[5] * inv + bf2f((unsigned short)(z.z >> 16)) + b1.y;
                r6 = rr[6] * inv + bf2f((unsigned short)(z.w & 0xffffu)) + b1.z;
                r7 = rr[7] * inv + bf2f((unsigned short)(z.w >> 16)) + b1.w;
                r0 = 1.0f / (1.0f + __expf(-r0));
                r1 = 1.0f / (1.0f + __expf(-r1));
                r2 = 1.0f / (1.0f + __expf(-r2));
                r3 = 1.0f / (1.0f + __expf(-r3));
                r4 = 1.0f / (1.0f + __expf(-r4));
                r5 = 1.0f / (1.0f + __expf(-r5));
                r6 = 1.0f / (1.0f + __expf(-r6));
                r7 = 1.0f / (1.0f + __expf(-r7));
            } else {
                r0 = rr[0] * inv; r1 = rr[1] * inv;
                r2 = rr[2] * inv; r3 = rr[3] * inv;
                r4 = rr[4] * inv; r5 = rr[5] * inv;
                r6 = rr[6] * inv; r7 = rr[7] * inv;
            }
            uint4 p;
            p.x = (unsigned int)(unsigned short)f2bf(r0) |
                  ((unsigned int)(unsigned short)f2bf(r1) << 16);
            p.y = (unsigned int)(unsigned short)f2bf(r2) |
                  ((unsigned int)(unsigned short)f2bf(r3) << 16);
            p.z = (unsigned int)(unsigned short)f2bf(r4) |
                  ((unsigned int)(unsigned short)f2bf(r5) << 16);
            p.w = (unsigned int)(unsigned short)f2bf(r6) |
                  ((unsigned int)(unsigned short)f2bf(r7) << 16);
            *(uint4*)(out + (size_t)node * 64 + c * 8) = p;
        }
    }
}

// ---------------------------------------------------------------------------
extern "C" void kernel_launch(void* const* d_in, const int* in_sizes, int n_in,
                              void* d_out, int out_size, void* d_ws,
                              size_t ws_size, hipStream_t stream) {
    const float* x = (const float*)d_in[0];
    const int* ei = (const int*)d_in[1];
    const float* W1l = (const float*)d_in[2];
    const float* b1 = (const float*)d_in[3];
    const float* W1r = (const float*)d_in[4];
    const float* W2l = (const float*)d_in[5];
    const float* b2 = (const float*)d_in[6];
    const float* W2r = (const float*)d_in[7];
    float* out = (float*)d_out;

    const int n = in_sizes[0] / N_FEAT;  // 100000
    const int ne = in_sizes[1] / 2;      // 600000

    const int nbe = (ne + NE_BLK - 1) / NE_BLK;   // 293 edge blocks
    const int nbuck = (n + 255) >> 8;             // 391 buckets
    const int tot = nbuck * nbe;                  // count-matrix size

    // ws layout
    unsigned short* zl1 = (unsigned short*)d_ws;
    unsigned short* zr1 = zl1 + (size_t)n * HID;
    unsigned short* h = zr1 + (size_t)n * HID;
    unsigned short* aggh = h + (size_t)n * HID;
    unsigned short* wt1 = aggh + (size_t)n * HID;
    unsigned short* wt2 = wt1 + 128 * 128;
    int* off = (int*)(wt2 + 48 * 128);
    int* csr = off + (n + 1);
    int* ebuf = csr + ne;
    int* bh = ebuf + ne;
    int* sbase = bh + tot;
    int* bsums = sbase + (tot + 1);
    int* flags = bsums + 256;

    const int gblocks = (n + 63) / 64;            // 1563
    const int ablocks = (n + 7) / 8;              // 12500 (8 nodes/block)
    const int nsb = (tot + 2047) / 2048;          // 56 scan blocks

    // 1) weight prep + bucket histogram + flag zero
    prep_hist<<<nbe, 256, 0, stream>>>(W1l, W1r, W2l, W2r, wt1, wt2, flags,
                                       ei, ne, n, bh, nbe);
    // 2) layer-1 GEMM
    gemm_mfma<N_FEAT, HID, true><<<gblocks, 256, 0, stream>>>(x, wt1, zl1, zr1, n);
    // 3-5) atomic-free CSR build
    scan_fused<<<nsb, 256, 0, stream>>>(bh, sbase, tot, bsums, flags);
    bucket_scatter<<<nbe, 256, 0, stream>>>(ei, ne, n, sbase, ebuf, nbe);
    bucket_build<<<nbuck, 256, 0, stream>>>(ebuf, sbase, nbe, n, ne, off, csr);
    // 6) layer-1 aggregate -> h
    agg64_kernel<0><<<ablocks, 256, 0, stream>>>(zl1, zr1, off, csr, b1, h, n);
    // 7) layer-2 aggregate -> aggh (pure mean)
    agg64_kernel<1><<<ablocks, 256, 0, stream>>>(h, nullptr, off, csr, nullptr,
                                                 aggh, n);
    // 8) layer-2 cat-GEMM -> out (fp32, bias fused)
    gemm2cat<<<gblocks, 256, 0, stream>>>(aggh, h, wt2, b2, out, n);
}

// Round 5
// 216.612 us; speedup vs baseline: 1.1625x; 1.0063x over previous
//
#include <hip/hip_runtime.h>
#include <hip/hip_bf16.h>

// GraphSAGE 2-layer forward — CSR-gather + bf16 MFMA GEMMs.
//   zl = x@W1l, zr = x@W1r      (bf16 MFMA, SPLIT packed arrays [n,64])
//   h  = sigmoid(csr_mean(zl) + zr + b1)        (h bf16 [n,64])
//   out = [mean(h) | h] @ [W2l;W2r] + b2        (fused gather+cat-GEMM)
//
// R5 changes vs 218µs:
//  - Both aggregators restructured to 64-node TILE blocks: block loads its
//    contiguous csr range ONCE (coalesced) into an LDS edge list, removing
//    the per-wave off->csr->gather dependent-latency chain.
//  - agg(h) + layer-2 cat-GEMM fused into ONE kernel: gather-mean writes
//    bf16 directly into the MFMA A-tile (left half), h staged right half.
//    Deletes the aggh round trip (25 MB) and a dispatch.
//  - bucket_scatter fused with gemm1 as heterogeneous blocks (independent
//    work, no global-atomic wall). 8 -> 6 dispatches.

#define N_FEAT 128
#define HID 64
#define NCLS 40
#define NE_BLK 2048
#define ECAP 1536

typedef short short8 __attribute__((ext_vector_type(8)));
typedef float floatx4 __attribute__((ext_vector_type(4)));

static __device__ __forceinline__ short f2bf(float x) {
    __hip_bfloat16 h = __float2bfloat16(x);
    return __builtin_bit_cast(short, h);
}
static __device__ __forceinline__ float bf2f(unsigned short u) {
    unsigned int v = ((unsigned int)u) << 16;
    return __builtin_bit_cast(float, v);
}
static __device__ __forceinline__ void acc8(float* a, uint4 v, float w) {
    a[0] = fmaf(w, bf2f((unsigned short)(v.x & 0xffffu)), a[0]);
    a[1] = fmaf(w, bf2f((unsigned short)(v.x >> 16)), a[1]);
    a[2] = fmaf(w, bf2f((unsigned short)(v.y & 0xffffu)), a[2]);
    a[3] = fmaf(w, bf2f((unsigned short)(v.y >> 16)), a[3]);
    a[4] = fmaf(w, bf2f((unsigned short)(v.z & 0xffffu)), a[4]);
    a[5] = fmaf(w, bf2f((unsigned short)(v.z >> 16)), a[5]);
    a[6] = fmaf(w, bf2f((unsigned short)(v.w & 0xffffu)), a[6]);
    a[7] = fmaf(w, bf2f((unsigned short)(v.w >> 16)), a[7]);
}

// ---------------------------------------------------------------------------
// Weight prep (wt1 [128][128], wt2cat [48][128] = [W2l;W2r]^T padded) +
// bucket histogram (LDS bins, key = dst>>8) + scan-flag zero. One dispatch.
// ---------------------------------------------------------------------------
__global__ void prep_hist(const float* __restrict__ W1l, const float* __restrict__ W1r,
                          const float* __restrict__ W2l, const float* __restrict__ W2r,
                          unsigned short* __restrict__ wt1,
                          unsigned short* __restrict__ wt2,
                          int* __restrict__ flags,
                          const int* __restrict__ ei, int ne, int n,
                          int* __restrict__ bh, int nbe) {
    __shared__ int bins[512];
    const int b = blockIdx.x, t = threadIdx.x;
    const int nbuck = (n + 255) >> 8;
    for (int i = t; i < nbuck; i += 256) bins[i] = 0;
    __syncthreads();
    const int e0 = b * NE_BLK;
    const int lim = (e0 + NE_BLK < ne) ? (e0 + NE_BLK) : ne;
    for (int e = e0 + t; e < lim; e += 256)
        atomicAdd(&bins[ei[ne + e] >> 8], 1);

    int i = b * 256 + t;
    if (i < 128 * 128) {
        int nn = i >> 7, k = i & 127;
        float v = (nn < 64) ? W1l[k * 64 + nn] : W1r[k * 64 + (nn - 64)];
        wt1[nn * 128 + k] = (unsigned short)f2bf(v);
    } else if (i < 128 * 128 + 48 * 128) {
        int j = i - 128 * 128;
        int nn = j >> 7, k = j & 127;
        float v = 0.f;
        if (nn < 40)
            v = (k < 64) ? W2l[k * 40 + nn] : W2r[(k - 64) * 40 + nn];
        wt2[nn * 128 + k] = (unsigned short)f2bf(v);
    }
    if (i < 256) flags[i] = 0;

    __syncthreads();
    for (int j = t; j < nbuck; j += 256) bh[j * nbe + b] = bins[j];
}

// ---------------------------------------------------------------------------
// Lookback exclusive scan: pre[0]=0, pre[i]=sum(in[0..i-1]).
// ---------------------------------------------------------------------------
__global__ void scan_fused(const int* __restrict__ in, int* __restrict__ pre,
                           int m, int* __restrict__ bsums,
                           int* __restrict__ flags) {
    __shared__ int lds[256];
    __shared__ int look[128];
    __shared__ int sprefix;
    const int b = blockIdx.x, t = threadIdx.x;
    const int base = b * 2048 + t * 8;
    int v[8], s = 0;
#pragma unroll
    for (int i = 0; i < 8; ++i) {
        int idx = base + i;
        v[i] = (idx < m) ? in[idx] : 0;
        s += v[i];
    }
    lds[t] = s;
    __syncthreads();
    for (int o = 1; o < 256; o <<= 1) {
        int y = (t >= o) ? lds[t - o] : 0;
        __syncthreads();
        lds[t] += y;
        __syncthreads();
    }
    if (t == 255) {
        __hip_atomic_store(&bsums[b], lds[255], __ATOMIC_RELEASE,
                           __HIP_MEMORY_SCOPE_AGENT);
        __hip_atomic_store(&flags[b], 1, __ATOMIC_RELEASE,
                           __HIP_MEMORY_SCOPE_AGENT);
    }
    if (t < 128) look[t] = 0;
    __syncthreads();
    if (t < b) {
        while (__hip_atomic_load(&flags[t], __ATOMIC_ACQUIRE,
                                 __HIP_MEMORY_SCOPE_AGENT) == 0) {}
        look[t] = __hip_atomic_load(&bsums[t], __ATOMIC_RELAXED,
                                    __HIP_MEMORY_SCOPE_AGENT);
    }
    __syncthreads();
    if (t == 0) {
        int p = 0;
        for (int i = 0; i < b; ++i) p += look[i];
        sprefix = p;
    }
    __syncthreads();
    int run = ((t == 0) ? 0 : lds[t - 1]) + sprefix;
#pragma unroll
    for (int i = 0; i < 8; ++i) {
        run += v[i];
        int idx = base + i;
        if (idx < m) pre[idx + 1] = run;
    }
    if (b == 0 && t == 0) pre[0] = 0;
}

// ---------------------------------------------------------------------------
// Layer-1 GEMM body (smem-pointer form so it can share a heterogeneous
// kernel with bucket_scatter). K=128, M=128 (cols [0,64)->Zl, [64,128)->Zr).
// ---------------------------------------------------------------------------
static __device__ __forceinline__ void gemm1_body(
    short* __restrict__ smem, const float* __restrict__ x,
    const unsigned short* __restrict__ Wt, unsigned short* __restrict__ Zl,
    unsigned short* __restrict__ Zr, int n, int bid) {
    constexpr int K = 128, LDA = K + 8, M = 128, MT = 8, KS = 4, QROW = 16;
    short* At = smem;             // 64 x LDA
    short* Bt = smem + 64 * LDA;  // 128 x LDA
    const int t = threadIdx.x;
    const int nodeBase = bid * 64;

    for (int q = t; q < 64 * QROW; q += 256) {
        int row = q / QROW;
        int k0 = (q % QROW) * 8;
        int node = nodeBase + row;
        short8 s = {0, 0, 0, 0, 0, 0, 0, 0};
        if (node < n) {
            const float* A = x + (size_t)node * K + k0;
            float4 v0 = *(const float4*)A;
            float4 v1 = *(const float4*)(A + 4);
            s[0] = f2bf(v0.x); s[1] = f2bf(v0.y);
            s[2] = f2bf(v0.z); s[3] = f2bf(v0.w);
            s[4] = f2bf(v1.x); s[5] = f2bf(v1.y);
            s[6] = f2bf(v1.z); s[7] = f2bf(v1.w);
        }
        *(short8*)&At[row * LDA + k0] = s;
    }
    for (int q = t; q < M * QROW; q += 256) {
        int row = q / QROW;
        int k0 = (q % QROW) * 8;
        *(short8*)&Bt[row * LDA + k0] =
            *(const short8*)((const short*)Wt + (size_t)row * K + k0);
    }
    __syncthreads();

    const int wave = t >> 6;
    const int lane = t & 63;
    const int m0 = wave * 16;
    const int fl = lane & 15;
    const int quad = lane >> 4;

    floatx4 acc[MT];
#pragma unroll
    for (int nt = 0; nt < MT; ++nt) acc[nt] = (floatx4){0.f, 0.f, 0.f, 0.f};

#pragma unroll
    for (int ks = 0; ks < KS; ++ks) {
        const int kb = ks * 32 + quad * 8;
        short8 a = *(const short8*)&At[(m0 + fl) * LDA + kb];
#pragma unroll
        for (int nt = 0; nt < MT; ++nt) {
            short8 b = *(const short8*)&Bt[(nt * 16 + fl) * LDA + kb];
            acc[nt] = __builtin_amdgcn_mfma_f32_16x16x32_bf16(a, b, acc[nt], 0, 0, 0);
        }
    }

#pragma unroll
    for (int nt = 0; nt < MT; ++nt) {
        const int col = nt * 16 + fl;
#pragma unroll
        for (int r = 0; r < 4; ++r) {
            int node = nodeBase + m0 + quad * 4 + r;
            if (node < n) {
                unsigned short v = (unsigned short)f2bf(acc[nt][r]);
                if (col < HID)
                    Zl[(size_t)node * HID + col] = v;
                else
                    Zr[(size_t)node * HID + (col - HID)] = v;
            }
        }
    }
}

// Heterogeneous launch: blocks [0,nbe) = bucket scatter, rest = layer-1 GEMM.
// Both depend only on {prep_hist, scan_fused}; overlapping them hides the
// scatter's scattered-store latency under the GEMM's MFMA/BW work.
__global__ __launch_bounds__(256) void scatter_gemm1(
    const int* __restrict__ ei, int ne, int n, const int* __restrict__ sbase,
    int* __restrict__ ebuf, int nbe, const float* __restrict__ x,
    const unsigned short* __restrict__ wt1, unsigned short* __restrict__ zl,
    unsigned short* __restrict__ zr) {
    __shared__ __align__(16) short smem[(64 + 128) * 136];
    const int b = blockIdx.x;
    if (b < nbe) {
        int* bins = (int*)smem;
        const int t = threadIdx.x;
        const int nbuck = (n + 255) >> 8;
        for (int i = t; i < nbuck; i += 256) bins[i] = 0;
        __syncthreads();
        const int e0 = b * NE_BLK;
        const int lim = (e0 + NE_BLK < ne) ? (e0 + NE_BLK) : ne;
        for (int e = e0 + t; e < lim; e += 256) {
            int d = ei[ne + e];
            int s = ei[e];
            int bk = d >> 8;
            int r = atomicAdd(&bins[bk], 1);
            int p = sbase[bk * nbe + b] + r;
            ebuf[p] = (int)(((unsigned)(d & 255) << 24) | (unsigned)s);
        }
    } else {
        gemm1_body(smem, x, wt1, zl, zr, n, b - nbe);
    }
}

// one block per bucket: LDS 256-bin sub-histogram + scan -> off[] (coalesced)
// and csr reordered within the bucket's contiguous range.
__global__ void bucket_build(const int* __restrict__ ebuf,
                             const int* __restrict__ sbase, int nbe, int n,
                             int ne, int* __restrict__ off,
                             int* __restrict__ csr) {
    __shared__ int cnt[256];
    __shared__ int sc[256];
    __shared__ int pos[256];
    const int b = blockIdx.x;
    const int t = threadIdx.x;
    const int nbuck = (n + 255) >> 8;
    const int s0 = sbase[b * nbe];
    const int s1 = (b + 1 < nbuck) ? sbase[(b + 1) * nbe] : ne;
    cnt[t] = 0;
    __syncthreads();
    for (int i = s0 + t; i < s1; i += 256)
        atomicAdd(&cnt[((unsigned)ebuf[i]) >> 24], 1);
    __syncthreads();
    int v = cnt[t];
    sc[t] = v;
    __syncthreads();
    for (int o = 1; o < 256; o <<= 1) {
        int y = (t >= o) ? sc[t - o] : 0;
        __syncthreads();
        sc[t] += y;
        __syncthreads();
    }
    int g = b * 256 + t;
    if (g < n) off[g + 1] = s0 + sc[t];
    if (b == 0 && t == 0) off[0] = 0;
    pos[t] = s0 + sc[t] - v;  // exclusive
    __syncthreads();
    for (int i = s0 + t; i < s1; i += 256) {
        unsigned w = (unsigned)ebuf[i];
        int p = atomicAdd(&pos[w >> 24], 1);
        csr[p] = (int)(w & 0xFFFFFFu);
    }
}

// ---------------------------------------------------------------------------
// Layer-1 aggregate, 64-node tile per block. The block's 64 nodes own a
// CONTIGUOUS csr range -> load it once (coalesced) into an LDS edge list,
// then the dual-chain gather has no global-latency index dependency.
// h = sigmoid(mean(Zl) + Zr + bias), bf16 out.
// ---------------------------------------------------------------------------
__global__ __launch_bounds__(256) void agg_h(
    const unsigned short* __restrict__ Zl, const unsigned short* __restrict__ Zr,
    const int* __restrict__ off, const int* __restrict__ csr,
    const float* __restrict__ bias, unsigned short* __restrict__ hout, int n) {
    __shared__ int offs[65];
    __shared__ int elist[ECAP];
    const int t = threadIdx.x;
    const int base = blockIdx.x * 64;
    if (t < 65) {
        int idx = base + t;
        offs[t] = off[(idx <= n) ? idx : n];
    }
    __syncthreads();
    const int E0 = offs[0];
    const int nedge = offs[64] - E0;
    const bool direct = (nedge > ECAP);
    if (!direct)
        for (int j = t; j < nedge; j += 256) elist[j] = csr[E0 + j];
    __syncthreads();

    const int lane = t & 63;
    const int wave = t >> 6;
    const int g = lane >> 3, c = lane & 7;

    for (int p = 0; p < 8; ++p) {
        const int i0 = wave * 16 + 2 * p, i1 = i0 + 1;
        const int s0 = offs[i0] - E0, d0 = offs[i0 + 1] - offs[i0];
        const int s1 = offs[i1] - E0, d1 = offs[i1 + 1] - offs[i1];
        float a0[8], a1[8];
#pragma unroll
        for (int j = 0; j < 8; ++j) { a0[j] = 0.f; a1[j] = 0.f; }
        const int dm = (d0 > d1) ? d0 : d1;
        for (int r0 = 0; r0 < dm; r0 += 8) {
            const int r = r0 + g;
            int sl0 = s0 + ((r < d0) ? r : ((d0 > 0) ? d0 - 1 : 0));
            int sl1 = s1 + ((r < d1) ? r : ((d1 > 0) ? d1 - 1 : 0));
            int j0 = (d0 > 0) ? (direct ? csr[E0 + sl0] : elist[sl0]) : 0;
            int j1 = (d1 > 0) ? (direct ? csr[E0 + sl1] : elist[sl1]) : 0;
            uint4 v0 = *(const uint4*)(Zl + (size_t)j0 * 64 + c * 8);
            uint4 v1 = *(const uint4*)(Zl + (size_t)j1 * 64 + c * 8);
            acc8(a0, v0, (r < d0) ? 1.f : 0.f);
            acc8(a1, v1, (r < d1) ? 1.f : 0.f);
        }
#pragma unroll
        for (int o = 8; o < 64; o <<= 1) {
#pragma unroll
            for (int j = 0; j < 8; ++j) {
                a0[j] += __shfl_xor(a0[j], o);
                a1[j] += __shfl_xor(a1[j], o);
            }
        }
        if (g < 2) {
            const int i = g ? i1 : i0;
            const int node = base + i;
            if (node < n) {
                const int dd = g ? d1 : d0;
                const float inv = 1.0f / fmaxf((float)dd, 1.0f);
                float rr[8];
#pragma unroll
                for (int j = 0; j < 8; ++j) rr[j] = (g ? a1[j] : a0[j]) * inv;
                uint4 z = *(const uint4*)(Zr + (size_t)node * 64 + c * 8);
                float4 b0 = ((const float4*)bias)[c * 2];
                float4 b1 = ((const float4*)bias)[c * 2 + 1];
                rr[0] += bf2f((unsigned short)(z.x & 0xffffu)) + b0.x;
                rr[1] += bf2f((unsigned short)(z.x >> 16)) + b0.y;
                rr[2] += bf2f((unsigned short)(z.y & 0xffffu)) + b0.z;
                rr[3] += bf2f((unsigned short)(z.y >> 16)) + b0.w;
                rr[4] += bf2f((unsigned short)(z.z & 0xffffu)) + b1.x;
                rr[5] += bf2f((unsigned short)(z.z >> 16)) + b1.y;
                rr[6] += bf2f((unsigned short)(z.w & 0xffffu)) + b1.z;
                rr[7] += bf2f((unsigned short)(z.w >> 16)) + b1.w;
#pragma unroll
                for (int j = 0; j < 8; ++j)
                    rr[j] = 1.0f / (1.0f + __expf(-rr[j]));
                uint4 pk;
                pk.x = (unsigned int)(unsigned short)f2bf(rr[0]) |
                       ((unsigned int)(unsigned short)f2bf(rr[1]) << 16);
                pk.y = (unsigned int)(unsigned short)f2bf(rr[2]) |
                       ((unsigned int)(unsigned short)f2bf(rr[3]) << 16);
                pk.z = (unsigned int)(unsigned short)f2bf(rr[4]) |
                       ((unsigned int)(unsigned short)f2bf(rr[5]) << 16);
                pk.w = (unsigned int)(unsigned short)f2bf(rr[6]) |
                       ((unsigned int)(unsigned short)f2bf(rr[7]) << 16);
                *(uint4*)(hout + (size_t)node * 64 + c * 8) = pk;
            }
        }
    }
}

// ---------------------------------------------------------------------------
// Fused layer-2: gather-mean(h) written as bf16 straight into the MFMA
// A-tile left half; h staged into the right half; K=128 cat-GEMM with
// wt2cat [48][128]; out = A@B + b2 (fp32 [n,40]).
// ---------------------------------------------------------------------------
__global__ __launch_bounds__(256) void agg_gemm2(
    const unsigned short* __restrict__ h, const unsigned short* __restrict__ Wt,
    const float* __restrict__ bias, const int* __restrict__ off,
    const int* __restrict__ csr, float* __restrict__ out, int n) {
    constexpr int LDA = 136;
    __shared__ __align__(16) short At[64 * LDA];
    __shared__ __align__(16) short Bt[48 * LDA];
    __shared__ int offs[65];
    __shared__ int elist[ECAP];
    const int t = threadIdx.x;
    const int base = blockIdx.x * 64;
    if (t < 65) {
        int idx = base + t;
        offs[t] = off[(idx <= n) ? idx : n];
    }
    __syncthreads();
    const int E0 = offs[0];
    const int nedge = offs[64] - E0;
    const bool direct = (nedge > ECAP);
    if (!direct)
        for (int j = t; j < nedge; j += 256) elist[j] = csr[E0 + j];
    // stage h rows into At[:, 64:128)
    for (int q = t; q < 64 * 8; q += 256) {
        int row = q >> 3, k0 = (q & 7) * 8;
        int node = base + row;
        short8 s = {0, 0, 0, 0, 0, 0, 0, 0};
        if (node < n) s = *(const short8*)(h + (size_t)node * 64 + k0);
        *(short8*)&At[row * LDA + 64 + k0] = s;
    }
    // stage Bt (48 x 128)
    for (int q = t; q < 48 * 16; q += 256) {
        int row = q >> 4, k0 = (q & 15) * 8;
        *(short8*)&Bt[row * LDA + k0] =
            *(const short8*)((const short*)Wt + (size_t)row * 128 + k0);
    }
    __syncthreads();

    // gather phase: mean over neighbors of h -> At[:, 0:64)
    const int lane = t & 63;
    const int wave = t >> 6;
    const int g = lane >> 3, c = lane & 7;
    for (int p = 0; p < 8; ++p) {
        const int i0 = wave * 16 + 2 * p, i1 = i0 + 1;
        const int s0 = offs[i0] - E0, d0 = offs[i0 + 1] - offs[i0];
        const int s1 = offs[i1] - E0, d1 = offs[i1 + 1] - offs[i1];
        float a0[8], a1[8];
#pragma unroll
        for (int j = 0; j < 8; ++j) { a0[j] = 0.f; a1[j] = 0.f; }
        const int dm = (d0 > d1) ? d0 : d1;
        for (int r0 = 0; r0 < dm; r0 += 8) {
            const int r = r0 + g;
            int sl0 = s0 + ((r < d0) ? r : ((d0 > 0) ? d0 - 1 : 0));
            int sl1 = s1 + ((r < d1) ? r : ((d1 > 0) ? d1 - 1 : 0));
            int j0 = (d0 > 0) ? (direct ? csr[E0 + sl0] : elist[sl0]) : 0;
            int j1 = (d1 > 0) ? (direct ? csr[E0 + sl1] : elist[sl1]) : 0;
            uint4 v0 = *(const uint4*)(h + (size_t)j0 * 64 + c * 8);
            uint4 v1 = *(const uint4*)(h + (size_t)j1 * 64 + c * 8);
            acc8(a0, v0, (r < d0) ? 1.f : 0.f);
            acc8(a1, v1, (r < d1) ? 1.f : 0.f);
        }
#pragma unroll
        for (int o = 8; o < 64; o <<= 1) {
#pragma unroll
            for (int j = 0; j < 8; ++j) {
                a0[j] += __shfl_xor(a0[j], o);
                a1[j] += __shfl_xor(a1[j], o);
            }
        }
        if (g < 2) {
            const int i = g ? i1 : i0;
            const int dd = g ? d1 : d0;
            const float inv = 1.0f / fmaxf((float)dd, 1.0f);
            short8 s;
#pragma unroll
            for (int j = 0; j < 8; ++j)
                s[j] = f2bf((g ? a1[j] : a0[j]) * inv);
            *(short8*)&At[i * LDA + c * 8] = s;  // mean=0 rows for node>=n
        }
    }
    __syncthreads();

    // MFMA: K=128, 3 col-tiles (48 cols, 40 valid)
    const int m0 = wave * 16;
    const int fl = lane & 15;
    const int quad = lane >> 4;
    floatx4 acc[3];
#pragma unroll
    for (int nt = 0; nt < 3; ++nt) acc[nt] = (floatx4){0.f, 0.f, 0.f, 0.f};
#pragma unroll
    for (int ks = 0; ks < 4; ++ks) {
        const int kb = ks * 32 + quad * 8;
        short8 a = *(const short8*)&At[(m0 + fl) * LDA + kb];
#pragma unroll
        for (int nt = 0; nt < 3; ++nt) {
            short8 b = *(const short8*)&Bt[(nt * 16 + fl) * LDA + kb];
            acc[nt] = __builtin_amdgcn_mfma_f32_16x16x32_bf16(a, b, acc[nt], 0, 0, 0);
        }
    }
#pragma unroll
    for (int nt = 0; nt < 3; ++nt) {
        const int col = nt * 16 + fl;
        if (col < NCLS) {
            float bv = bias[col];
#pragma unroll
            for (int r = 0; r < 4; ++r) {
                int node = base + m0 + quad * 4 + r;
                if (node < n)
                    out[(size_t)node * NCLS + col] = acc[nt][r] + bv;
            }
        }
    }
}

// ---------------------------------------------------------------------------
extern "C" void kernel_launch(void* const* d_in, const int* in_sizes, int n_in,
                              void* d_out, int out_size, void* d_ws,
                              size_t ws_size, hipStream_t stream) {
    const float* x = (const float*)d_in[0];
    const int* ei = (const int*)d_in[1];
    const float* W1l = (const float*)d_in[2];
    const float* b1 = (const float*)d_in[3];
    const float* W1r = (const float*)d_in[4];
    const float* W2l = (const float*)d_in[5];
    const float* b2 = (const float*)d_in[6];
    const float* W2r = (const float*)d_in[7];
    float* out = (float*)d_out;

    const int n = in_sizes[0] / N_FEAT;  // 100000
    const int ne = in_sizes[1] / 2;      // 600000

    const int nbe = (ne + NE_BLK - 1) / NE_BLK;   // 293 edge blocks
    const int nbuck = (n + 255) >> 8;             // 391 buckets
    const int tot = nbuck * nbe;                  // count-matrix size

    // ws layout
    unsigned short* zl1 = (unsigned short*)d_ws;
    unsigned short* zr1 = zl1 + (size_t)n * HID;
    unsigned short* h = zr1 + (size_t)n * HID;
    unsigned short* wt1 = h + (size_t)n * HID;
    unsigned short* wt2 = wt1 + 128 * 128;
    int* off = (int*)(wt2 + 48 * 128);
    int* csr = off + (n + 1);
    int* ebuf = csr + ne;
    int* bh = ebuf + ne;
    int* sbase = bh + tot;
    int* bsums = sbase + (tot + 1);
    int* flags = bsums + 256;

    const int gblocks = (n + 63) / 64;            // 1563
    const int nsb = (tot + 2047) / 2048;          // 56 scan blocks

    // 1) weight prep + bucket histogram + flag zero
    prep_hist<<<nbe, 256, 0, stream>>>(W1l, W1r, W2l, W2r, wt1, wt2, flags,
                                       ei, ne, n, bh, nbe);
    // 2) count-matrix scan
    scan_fused<<<nsb, 256, 0, stream>>>(bh, sbase, tot, bsums, flags);
    // 3) bucket scatter + layer-1 GEMM (independent, heterogeneous blocks)
    scatter_gemm1<<<nbe + gblocks, 256, 0, stream>>>(ei, ne, n, sbase, ebuf,
                                                     nbe, x, wt1, zl1, zr1);
    // 4) per-bucket CSR finalize
    bucket_build<<<nbuck, 256, 0, stream>>>(ebuf, sbase, nbe, n, ne, off, csr);
    // 5) layer-1 aggregate -> h
    agg_h<<<gblocks, 256, 0, stream>>>(zl1, zr1, off, csr, b1, h, n);
    // 6) fused layer-2 gather + cat-GEMM -> out
    agg_gemm2<<<gblocks, 256, 0, stream>>>(h, wt2, b2, off, csr, out, n);
}